// Round 4
// baseline (2348.975 us; speedup 1.0000x reference)
//
#include <hip/hip_runtime.h>
#include <hip/hip_bf16.h>
#include <stdint.h>

// Problem constants
#define B_ 4
#define T_ 2048
#define C_ 2048
#define H_ 16
#define DK_ 64
#define DV_ 128
#define BT_ (B_ * T_)   // 8192

typedef __attribute__((ext_vector_type(8))) __bf16 bf16x8;
typedef __attribute__((ext_vector_type(4))) float f32x4;

__device__ __forceinline__ unsigned short f2bf(float f) {
    union { float f; uint32_t u; } v; v.f = f;
    uint32_t u = v.u;
    uint32_t r = u + 0x7FFFu + ((u >> 16) & 1u);   // RNE
    return (unsigned short)(r >> 16);
}
__device__ __forceinline__ float bf2f(unsigned short h) {
    union { uint32_t u; float f; } v; v.u = ((uint32_t)h) << 16; return v.f;
}
__device__ __forceinline__ float siluf(float x) { return x / (1.f + expf(-x)); }

// hi = RNE bf16 of x; lo = trunc bf16 of (x - hi). x ≈ hi + lo to ~2^-17 rel.
__device__ __forceinline__ void split_hl(float x, unsigned short& h, unsigned short& l) {
    unsigned short hu = f2bf(x);
    float lo = x - bf2f(hu);
    h = hu;
    l = (unsigned short)(__float_as_uint(lo) >> 16);
}

// ---------------------------------------------------------------- casts
__global__ void cast_split_k(const float* __restrict__ in,
                             unsigned short* __restrict__ oh, unsigned short* __restrict__ ol, int n4) {
    int i = blockIdx.x * blockDim.x + threadIdx.x;
    if (i >= n4) return;
    float4 v = ((const float4*)in)[i];
    ushort4 h, l;
    split_hl(v.x, h.x, l.x); split_hl(v.y, h.y, l.y);
    split_hl(v.z, h.z, l.z); split_hl(v.w, h.w, l.w);
    ((ushort4*)oh)[i] = h;
    ((ushort4*)ol)[i] = l;
}

__global__ void cast_plain_k(const float* __restrict__ in, unsigned short* __restrict__ out, int n4) {
    int i = blockIdx.x * blockDim.x + threadIdx.x;
    if (i >= n4) return;
    float4 v = ((const float4*)in)[i];
    ushort4 o;
    o.x = f2bf(v.x); o.y = f2bf(v.y); o.z = f2bf(v.z); o.w = f2bf(v.w);
    ((ushort4*)out)[i] = o;
}

// ---------------------------------------------------------------- async global->LDS (16B/lane)
__device__ __forceinline__ void gld_lds16(const unsigned short* gptr,
                                          unsigned short* lds_base) {
    __builtin_amdgcn_global_load_lds(
        (const __attribute__((address_space(1))) uint32_t*)(uintptr_t)gptr,
        (__attribute__((address_space(3))) uint32_t*)(uint32_t)(uintptr_t)lds_base,
        16, 0, 0);
}

// ---------------------------------------------------------------- split-precision GEMM
// C[M,N] = A[M,K](f32) * W[N,K]^T where W pre-split (Wh+Wl bf16). A split to hi/lo
// bf16 at staging. DO_LO: 3-pass (AhWh+AhWl+AlWh, ~1e-4 rel); else hi-only bf16 GEMM.
template<bool DO_LO, bool F32OUT>
__global__ __launch_bounds__(256)
void gemm_split(const float* __restrict__ A, int lda,
                const unsigned short* __restrict__ Wh, const unsigned short* __restrict__ Wl,
                void* __restrict__ Cout, int M, int N, int K) {
    __shared__ __align__(16) unsigned short sAh[128 * 64];
    __shared__ __align__(16) unsigned short sAl[128 * 64];
    __shared__ __align__(16) unsigned short sWh[128 * 64];
    __shared__ __align__(16) unsigned short sWl[128 * 64];
    const int tid  = threadIdx.x;
    const int wave = tid >> 6;
    const int lane = tid & 63;
    const int wm = (wave >> 1) * 64;
    const int wn = (wave & 1) * 64;
    const int bm = blockIdx.y, bn = blockIdx.x;

    const int wrow = lane >> 3;        // W staging: row within 8-row group
    const int wcol = (lane & 7) * 8;   // k offset (8 bf16 = 16B)

    const float*          Ag = A  + (size_t)(bm * 128) * lda;
    const unsigned short* Whg = Wh + (size_t)(bn * 128) * K;
    const unsigned short* Wlg = DO_LO ? (Wl + (size_t)(bn * 128) * K) : nullptr;

    f32x4 acc[4][4];
#pragma unroll
    for (int i = 0; i < 4; i++)
#pragma unroll
        for (int j = 0; j < 4; j++) { acc[i][j][0]=0.f; acc[i][j][1]=0.f; acc[i][j][2]=0.f; acc[i][j][3]=0.f; }

    const int mrow = lane & 15;
    const int kq   = (lane >> 4) * 8;

    for (int k0 = 0; k0 < K; k0 += 64) {
        // A staging: 128x64 f32 tile -> split hi/lo bf16 in LDS. 8 float4/thread.
#pragma unroll
        for (int it = 0; it < 8; it++) {
            int idx = it * 256 + tid;
            int r   = idx >> 4;
            int c4  = (idx & 15) * 4;
            float4 v = *(const float4*)(Ag + (size_t)r * lda + k0 + c4);
            ushort4 h, l;
            split_hl(v.x, h.x, l.x); split_hl(v.y, h.y, l.y);
            split_hl(v.z, h.z, l.z); split_hl(v.w, h.w, l.w);
            *(ushort4*)(sAh + r * 64 + c4) = h;
            if (DO_LO) *(ushort4*)(sAl + r * 64 + c4) = l;
        }
        // W staging via async gld
#pragma unroll
        for (int i = 0; i < 4; i++) {
            int rbase = wave * 32 + i * 8;
            gld_lds16(Whg + (size_t)(rbase + wrow) * K + k0 + wcol, sWh + rbase * 64);
            if (DO_LO)
                gld_lds16(Wlg + (size_t)(rbase + wrow) * K + k0 + wcol, sWl + rbase * 64);
        }
        __syncthreads();
#pragma unroll
        for (int kk = 0; kk < 2; kk++) {
            bf16x8 afh[4], wfh[4];
#pragma unroll
            for (int i = 0; i < 4; i++)
                afh[i] = *(const bf16x8*)(sAh + (wm + i * 16 + mrow) * 64 + kk * 32 + kq);
#pragma unroll
            for (int j = 0; j < 4; j++)
                wfh[j] = *(const bf16x8*)(sWh + (wn + j * 16 + mrow) * 64 + kk * 32 + kq);
#pragma unroll
            for (int i = 0; i < 4; i++)
#pragma unroll
                for (int j = 0; j < 4; j++)
                    acc[i][j] = __builtin_amdgcn_mfma_f32_16x16x32_bf16(afh[i], wfh[j], acc[i][j], 0, 0, 0);
            if (DO_LO) {
                bf16x8 afl[4], wfl[4];
#pragma unroll
                for (int i = 0; i < 4; i++)
                    afl[i] = *(const bf16x8*)(sAl + (wm + i * 16 + mrow) * 64 + kk * 32 + kq);
#pragma unroll
                for (int j = 0; j < 4; j++)
                    wfl[j] = *(const bf16x8*)(sWl + (wn + j * 16 + mrow) * 64 + kk * 32 + kq);
#pragma unroll
                for (int i = 0; i < 4; i++)
#pragma unroll
                    for (int j = 0; j < 4; j++) {
                        acc[i][j] = __builtin_amdgcn_mfma_f32_16x16x32_bf16(afh[i], wfl[j], acc[i][j], 0, 0, 0);
                        acc[i][j] = __builtin_amdgcn_mfma_f32_16x16x32_bf16(afl[i], wfh[j], acc[i][j], 0, 0, 0);
                    }
            }
        }
        __syncthreads();
    }
    // epilogue: D[m][n]: m=(lane>>4)*4+r, n=lane&15 (m89-verified)
    const int r0 = (lane >> 4) * 4;
    const int cn = lane & 15;
#pragma unroll
    for (int i = 0; i < 4; i++) {
#pragma unroll
        for (int r = 0; r < 4; r++) {
            int row = bm * 128 + wm + i * 16 + r0 + r;
            size_t base = (size_t)row * N + bn * 128 + wn + cn;
            if constexpr (F32OUT) {
                float* Crow = (float*)Cout + base;
#pragma unroll
                for (int j = 0; j < 4; j++) Crow[j * 16] = acc[i][j][r];
            } else {
                unsigned short* Crow = (unsigned short*)Cout + base;
#pragma unroll
                for (int j = 0; j < 4; j++) Crow[j * 16] = f2bf(acc[i][j][r]);
            }
        }
    }
}

// ---------------------------------------------------------------- plain bf16 GEMM (final): A bf16 w/ lda, out f32
__global__ __launch_bounds__(256)
void gemm_bt(const unsigned short* __restrict__ A, int lda, const unsigned short* __restrict__ W,
             float* __restrict__ C, int M, int N, int K) {
    __shared__ __align__(16) unsigned short sA[128 * 64];
    __shared__ __align__(16) unsigned short sB[128 * 64];
    const int tid  = threadIdx.x;
    const int wave = tid >> 6;
    const int lane = tid & 63;
    const int wm = (wave >> 1) * 64;
    const int wn = (wave & 1) * 64;
    const int bm = blockIdx.y, bn = blockIdx.x;
    const int srow = lane >> 3;
    const int scol = (lane & 7) * 8;

    const unsigned short* Ag = A + (size_t)(bm * 128) * lda;
    const unsigned short* Wg = W + (size_t)(bn * 128) * K;

    f32x4 acc[4][4];
#pragma unroll
    for (int i = 0; i < 4; i++)
#pragma unroll
        for (int j = 0; j < 4; j++) { acc[i][j][0]=0.f; acc[i][j][1]=0.f; acc[i][j][2]=0.f; acc[i][j][3]=0.f; }

    const int mrow = lane & 15;
    const int kq   = (lane >> 4) * 8;

    for (int k0 = 0; k0 < K; k0 += 64) {
#pragma unroll
        for (int i = 0; i < 4; i++) {
            int rbase = wave * 32 + i * 8;
            gld_lds16(Ag + (size_t)(rbase + srow) * lda + k0 + scol, sA + rbase * 64);
            gld_lds16(Wg + (size_t)(rbase + srow) * K   + k0 + scol, sB + rbase * 64);
        }
        __syncthreads();
#pragma unroll
        for (int kk = 0; kk < 2; kk++) {
            bf16x8 af[4], bfr[4];
#pragma unroll
            for (int i = 0; i < 4; i++)
                af[i] = *(const bf16x8*)(sA + (wm + i * 16 + mrow) * 64 + kk * 32 + kq);
#pragma unroll
            for (int j = 0; j < 4; j++)
                bfr[j] = *(const bf16x8*)(sB + (wn + j * 16 + mrow) * 64 + kk * 32 + kq);
#pragma unroll
            for (int i = 0; i < 4; i++)
#pragma unroll
                for (int j = 0; j < 4; j++)
                    acc[i][j] = __builtin_amdgcn_mfma_f32_16x16x32_bf16(af[i], bfr[j], acc[i][j], 0, 0, 0);
        }
        __syncthreads();
    }
    const int r0 = (lane >> 4) * 4;
    const int cn = lane & 15;
#pragma unroll
    for (int i = 0; i < 4; i++) {
#pragma unroll
        for (int r = 0; r < 4; r++) {
            int row = bm * 128 + wm + i * 16 + r0 + r;
            float* Crow = C + (size_t)row * N + bn * 128 + wn + cn;
#pragma unroll
            for (int j = 0; j < 4; j++)
                Crow[j * 16] = acc[i][j][r];
        }
    }
}

// ---------------------------------------------------------------- per-head gates (exact fp32)
__device__ __forceinline__ float softplusf(float x) {
    return (x > 20.f) ? x : log1pf(expf(x));
}

__global__ __launch_bounds__(256)
void gates_k(const float* __restrict__ x, const float* __restrict__ a_w, const float* __restrict__ b_w,
             const float* __restrict__ b_bias, const float* __restrict__ beta_bias,
             const float* __restrict__ A_log, const float* __restrict__ dt_bias,
             float* __restrict__ g, float* __restrict__ beta) {
    int bt = blockIdx.x;
    int wave = threadIdx.x >> 6, lane = threadIdx.x & 63;
    const float* xr = x + (size_t)bt * C_;
#pragma unroll
    for (int dd = 0; dd < 8; dd++) {
        int d = wave * 8 + dd;
        int h = d & 15;
        const float* wr = (d < 16 ? a_w : b_w) + (size_t)h * C_;
        float acc = 0.f;
#pragma unroll
        for (int it = 0; it < 8; it++) {
            float4 xv = ((const float4*)xr)[lane + it * 64];
            float4 wv = ((const float4*)wr)[lane + it * 64];
            acc += xv.x * wv.x + xv.y * wv.y + xv.z * wv.z + xv.w * wv.w;
        }
        acc += __shfl_xor(acc, 1);  acc += __shfl_xor(acc, 2);  acc += __shfl_xor(acc, 4);
        acc += __shfl_xor(acc, 8);  acc += __shfl_xor(acc, 16); acc += __shfl_xor(acc, 32);
        if (lane == 0) {
            if (d < 16) {
                g[(size_t)bt * H_ + h] = -expf(A_log[h]) * softplusf(acc + dt_bias[h]);
            } else {
                float s = 1.f / (1.f + expf(-(acc + b_bias[h] + beta_bias[h])));
                beta[(size_t)bt * H_ + h] = 2.f * s;
            }
        }
    }
}

// ---------------------------------------------------------------- fused conv+silu+l2norm+scan (all f32)
// 128 blocks (b,h,vh). Reads raw q,k from qk (d_out f32, [q|k] cols) and raw v from
// vbuf; causal dwconv(4)+silu computed in-LDS with 3-row carry across chunks;
// writes o f32 in-place over consumed v rows of vbuf.
#define CT_ 32
__global__ __launch_bounds__(256)
void scan_fused(const float* __restrict__ qk, float* __restrict__ vbuf,
                const float* __restrict__ qcw, const float* __restrict__ kcw, const float* __restrict__ vcw,
                const float* __restrict__ g, const float* __restrict__ beta) {
    int blk = blockIdx.x;
    int vh  = blk & 1;
    int bh  = blk >> 1;
    int b   = bh >> 4;
    int h   = bh & 15;
    int tid = threadIdx.x;
    int dkq = tid & 3;
    int dvl = tid >> 2;
    int dk0 = dkq * 16;

    __shared__ __align__(16) float rawq[(CT_ + 3) * 64];
    __shared__ __align__(16) float rawk[(CT_ + 3) * 64];
    __shared__ __align__(16) float rawv[(CT_ + 3) * 64];
    __shared__ __align__(16) float sq[CT_ * 68];
    __shared__ __align__(16) float sk[CT_ * 68];
    __shared__ __align__(16) float sv[CT_ * 68];
    __shared__ __align__(16) float wqs[64 * 4];
    __shared__ __align__(16) float wks[64 * 4];
    __shared__ __align__(16) float wvs[64 * 4];
    __shared__ float sg[CT_];
    __shared__ float sb[CT_];

    // preload conv weights for this head
    if (tid < 64) {
        *(float4*)(wqs + tid * 4) = *(const float4*)(qcw + (size_t)(h * 64 + tid) * 4);
        *(float4*)(wks + tid * 4) = *(const float4*)(kcw + (size_t)(h * 64 + tid) * 4);
        *(float4*)(wvs + tid * 4) = *(const float4*)(vcw + (size_t)(h * 128 + vh * 64 + tid) * 4);
    }
    // zero carry-source rows CT..CT+3 (first chunk's causal zero-pad)
    if (tid < 192) {
        int bsel = tid >> 6, c = tid & 63;
        float* rb = bsel == 0 ? rawq : (bsel == 1 ? rawk : rawv);
#pragma unroll
        for (int j = 0; j < 3; j++) rb[(CT_ + j) * 64 + c] = 0.f;
    }

    float S[16];
#pragma unroll
    for (int i = 0; i < 16; i++) S[i] = 0.f;

    const size_t qbase = (size_t)b * T_ * 2048 + h * 64;
    const size_t kbase = qbase + 1024;
    const size_t vbase = (size_t)b * T_ * 2048 + h * 128 + vh * 64;
    const size_t gbase = (size_t)b * T_ * H_ + h;

    for (int tc = 0; tc < T_; tc += CT_) {
        __syncthreads();   // prev chunk fully consumed (raw + s-bufs)
        // carry last 3 raw rows to front
        if (tid < 192) {
            int bsel = tid >> 6, c = tid & 63;
            float* rb = bsel == 0 ? rawq : (bsel == 1 ? rawk : rawv);
#pragma unroll
            for (int j = 0; j < 3; j++) rb[j * 64 + c] = rb[(CT_ + j) * 64 + c];
        }
        __syncthreads();
        // fresh stage: rows [tc, tc+CT) of raw q,k,v + gates
#pragma unroll
        for (int u = 0; u < 2; u++) {
            int idx = u * 256 + tid;
            int r   = idx >> 4;
            int c4  = (idx & 15) * 4;
            size_t row = (size_t)(tc + r) * 2048;
            *(float4*)(rawq + (3 + r) * 64 + c4) = *(const float4*)(qk + qbase + row + c4);
            *(float4*)(rawk + (3 + r) * 64 + c4) = *(const float4*)(qk + kbase + row + c4);
            *(float4*)(rawv + (3 + r) * 64 + c4) = *(const float4*)(vbuf + vbase + row + c4);
        }
        if (tid < CT_)           sg[tid]       = expf(g[gbase + (size_t)(tc + tid) * H_]);
        else if (tid < 2 * CT_)  sb[tid - CT_] = beta[gbase + (size_t)(tc + tid - CT_) * H_];
        __syncthreads();
        // conv(4) + silu: out row r uses raw rows r..r+3 (raw[3+r]=x[tc+r])
        {
            int c  = tid & 63;
            int r0 = tid >> 6;
#pragma unroll
            for (int it = 0; it < 8; it++) {
                int r = r0 + it * 4;
                float aq = 0.f, ak = 0.f, av = 0.f;
#pragma unroll
                for (int j = 0; j < 4; j++) {
                    aq += wqs[c * 4 + j] * rawq[(r + j) * 64 + c];
                    ak += wks[c * 4 + j] * rawk[(r + j) * 64 + c];
                    av += wvs[c * 4 + j] * rawv[(r + j) * 64 + c];
                }
                sq[r * 68 + c] = siluf(aq);
                sk[r * 68 + c] = siluf(ak);
                sv[r * 68 + c] = siluf(av);
            }
        }
        __syncthreads();
        // l2norm q,k rows (8 lanes/row)
        {
            int r = tid >> 3;
            int j = tid & 7;
            float* kr = sk + r * 68 + j * 8;
            float* qr = sq + r * 68 + j * 8;
            float ssk = 0.f, ssq = 0.f;
#pragma unroll
            for (int i = 0; i < 8; i++) { float a = kr[i]; ssk += a * a; float c2 = qr[i]; ssq += c2 * c2; }
            ssk += __shfl_xor(ssk, 1); ssk += __shfl_xor(ssk, 2); ssk += __shfl_xor(ssk, 4);
            ssq += __shfl_xor(ssq, 1); ssq += __shfl_xor(ssq, 2); ssq += __shfl_xor(ssq, 4);
            float rk = rsqrtf(ssk + 1e-6f);
            float rq = rsqrtf(ssq + 1e-6f) * 0.125f;   // fold SCALE = DK^-0.5
#pragma unroll
            for (int i = 0; i < 8; i++) { kr[i] *= rk; qr[i] *= rq; }
        }
        __syncthreads();
        // sequential steps
        for (int t2 = 0; t2 < CT_; t2++) {
            float dec = sg[t2];
            float btt = sb[t2];
            float vt  = sv[t2 * 68 + dvl];
            float kf[16], qf[16];
#pragma unroll
            for (int u = 0; u < 4; u++) {
                float4 k4 = ((const float4*)(sk + t2 * 68 + dk0))[u];
                float4 q4 = ((const float4*)(sq + t2 * 68 + dk0))[u];
                kf[u*4+0]=k4.x; kf[u*4+1]=k4.y; kf[u*4+2]=k4.z; kf[u*4+3]=k4.w;
                qf[u*4+0]=q4.x; qf[u*4+1]=q4.y; qf[u*4+2]=q4.z; qf[u*4+3]=q4.w;
            }
            float m0=0.f, m1=0.f, m2=0.f, m3=0.f;
#pragma unroll
            for (int u = 0; u < 4; u++) {
                S[u*4+0] *= dec; m0 += kf[u*4+0] * S[u*4+0];
                S[u*4+1] *= dec; m1 += kf[u*4+1] * S[u*4+1];
                S[u*4+2] *= dec; m2 += kf[u*4+2] * S[u*4+2];
                S[u*4+3] *= dec; m3 += kf[u*4+3] * S[u*4+3];
            }
            float m = (m0 + m1) + (m2 + m3);
            m += __shfl_xor(m, 1);
            m += __shfl_xor(m, 2);
            float delta = (vt - m) * btt;
            float o0=0.f, o1=0.f, o2=0.f, o3=0.f;
#pragma unroll
            for (int u = 0; u < 4; u++) {
                S[u*4+0] += kf[u*4+0] * delta; o0 += qf[u*4+0] * S[u*4+0];
                S[u*4+1] += kf[u*4+1] * delta; o1 += qf[u*4+1] * S[u*4+1];
                S[u*4+2] += kf[u*4+2] * delta; o2 += qf[u*4+2] * S[u*4+2];
                S[u*4+3] += kf[u*4+3] * delta; o3 += qf[u*4+3] * S[u*4+3];
            }
            float ov = (o0 + o1) + (o2 + o3);
            ov += __shfl_xor(ov, 1);
            ov += __shfl_xor(ov, 2);
            if (dkq == 0)
                vbuf[vbase + (size_t)(tc + t2) * 2048 + dvl] = ov;  // o over consumed v
        }
    }
}

// ---------------------------------------------------------------- postnorm: rms(o)*silu(g_out) -> og bf16
// o f32 in vbuf rows (stride 2048 f32); g_out bf16 in d_out (stride 2048 ushort);
// og bf16 written IN-PLACE over vbuf rows (stride 4096 ushort).
__global__ __launch_bounds__(256)
void postnorm_k(float* __restrict__ vbuf, const unsigned short* __restrict__ gout) {
    int bt  = blockIdx.x;
    int tid = threadIdx.x;
    const float* orow = vbuf + (size_t)bt * 2048 + tid * 8;
    float4 a = ((const float4*)orow)[0];
    float4 c = ((const float4*)orow)[1];
    float ss = a.x*a.x + a.y*a.y + a.z*a.z + a.w*a.w
             + c.x*c.x + c.y*c.y + c.z*c.z + c.w*c.w;
    ss += __shfl_xor(ss, 1); ss += __shfl_xor(ss, 2); ss += __shfl_xor(ss, 4); ss += __shfl_xor(ss, 8);
    float rms = rsqrtf(ss * (1.f / 128.f) + 1.1920928955078125e-07f);
    const unsigned short* grow = gout + (size_t)bt * 2048 + tid * 8;
    ushort4 g1 = ((const ushort4*)grow)[0];
    ushort4 g2 = ((const ushort4*)grow)[1];
    ushort4 r0, r1;
    r0.x = f2bf(a.x * rms * siluf(bf2f(g1.x)));
    r0.y = f2bf(a.y * rms * siluf(bf2f(g1.y)));
    r0.z = f2bf(a.z * rms * siluf(bf2f(g1.z)));
    r0.w = f2bf(a.w * rms * siluf(bf2f(g1.w)));
    r1.x = f2bf(c.x * rms * siluf(bf2f(g2.x)));
    r1.y = f2bf(c.y * rms * siluf(bf2f(g2.y)));
    r1.z = f2bf(c.z * rms * siluf(bf2f(g2.z)));
    r1.w = f2bf(c.w * rms * siluf(bf2f(g2.w)));
    __syncthreads();   // all reads of this row done before in-place overwrite
    unsigned short* og = (unsigned short*)vbuf + (size_t)bt * 4096 + tid * 8;
    *(ushort4*)og       = r0;
    *(ushort4*)(og + 4) = r1;
}

// ---------------------------------------------------------------- launch
// ws (121 MiB peak):
//   [0,8)    qkw_h    [8,16)   qkw_l
//   [16,32)  vgw_h    [32,48)  vgw_l   (full 4096 rows; lo used for v-half only)
//   [48,56)  ow_bf
//   [56,120) vbuf f32: GEMM2v out -> o (scan, in-place) -> og bf16 (postnorm, stride 4096)
//   [120,121) gbuf, bbuf
// d_out (64 MiB f32): qk f32 (GEMM1) -> consumed by scan -> g_out bf16 [0,32MiB)
//   (GEMM2g, after scan) -> final f32 output (overwrites everything).
extern "C" void kernel_launch(void* const* d_in, const int* in_sizes, int n_in,
                              void* d_out, int out_size, void* d_ws, size_t ws_size,
                              hipStream_t stream) {
    (void)in_sizes; (void)n_in; (void)out_size; (void)ws_size;
    const float* x        = (const float*)d_in[0];
    const float* qk_w     = (const float*)d_in[1];
    const float* vg_w     = (const float*)d_in[2];
    const float* o_w      = (const float*)d_in[3];
    const float* a_w      = (const float*)d_in[4];
    const float* b_w      = (const float*)d_in[5];
    const float* b_bias   = (const float*)d_in[6];
    const float* beta_b   = (const float*)d_in[7];
    const float* A_log    = (const float*)d_in[8];
    const float* dt_bias  = (const float*)d_in[9];
    const float* q_conv_w = (const float*)d_in[10];
    const float* k_conv_w = (const float*)d_in[11];
    const float* v_conv_w = (const float*)d_in[12];

    char* ws = (char*)d_ws;
    unsigned short* qkw_h = (unsigned short*)(ws);
    unsigned short* qkw_l = (unsigned short*)(ws + (8u  << 20));
    unsigned short* vgw_h = (unsigned short*)(ws + (16u << 20));
    unsigned short* vgw_l = (unsigned short*)(ws + (32u << 20));
    unsigned short* ow_bf = (unsigned short*)(ws + (48u << 20));
    float*          vbuf  = (float*)(ws + (56u << 20));
    float*          gbuf  = (float*)(ws + (120u << 20));
    float*          bbuf  = (float*)(ws + (120u << 20) + (512u << 10));

    float* qkf            = (float*)d_out;                 // qk f32 (GEMM1)
    unsigned short* goutb = (unsigned short*)d_out;        // g_out bf16 (after scan)
    float* outp           = (float*)d_out;                 // final f32 output

    // 1) weight casts
    cast_split_k<<<(2048 * 2048 / 4 + 255) / 256, 256, 0, stream>>>(qk_w, qkw_h, qkw_l, 2048 * 2048 / 4);
    cast_split_k<<<(4096 * 2048 / 4 + 255) / 256, 256, 0, stream>>>(vg_w, vgw_h, vgw_l, 4096 * 2048 / 4);
    cast_plain_k<<<(2048 * 2048 / 4 + 255) / 256, 256, 0, stream>>>(o_w, ow_bf, 2048 * 2048 / 4);

    // 2) split-precision GEMMs: qk f32 -> d_out; v f32 -> vbuf
    gemm_split<true, true><<<dim3(16, 64), 256, 0, stream>>>(x, 2048, qkw_h, qkw_l, qkf, BT_, 2048, 2048);
    gemm_split<true, true><<<dim3(16, 64), 256, 0, stream>>>(x, 2048, vgw_h, vgw_l, vbuf, BT_, 2048, 2048);

    // 3) gates (exact fp32)
    gates_k<<<BT_, 256, 0, stream>>>(x, a_w, b_w, b_bias, beta_b, A_log, dt_bias, gbuf, bbuf);

    // 4) fused conv+silu+l2norm+scan -> o f32 in-place over vbuf
    scan_fused<<<B_ * H_ * 2, 256, 0, stream>>>(qkf, vbuf, q_conv_w, k_conv_w, v_conv_w, gbuf, bbuf);

    // 5) g_out = x @ vg_w[2048:].T, hi-only bf16 -> d_out[0,32MiB) (qk consumed)
    gemm_split<false, false><<<dim3(16, 64), 256, 0, stream>>>(
        x, 2048, vgw_h + (size_t)2048 * 2048, nullptr, goutb, BT_, 2048, 2048);

    // 6) postnorm -> og bf16 in-place over vbuf (stride 4096 ushort)
    postnorm_k<<<BT_, 256, 0, stream>>>(vbuf, goutb);

    // 7) final GEMM: og @ o_w.T -> d_out f32
    gemm_bt<<<dim3(16, 64), 256, 0, stream>>>((unsigned short*)vbuf, 4096, ow_bf, outp, BT_, 2048, 2048);
}